// Round 11
// baseline (147.682 us; speedup 1.0000x reference)
//
#include <hip/hip_runtime.h>

// Depth rasterization, MI355X — round 11.
// R10 post-mortem: 4px/lane model right (VALU ~16us) but occupancy fell to
// 22% (6400 1-wave blocks, non-uniform durations -> tails).  Invariant across
// R8/R10: VALU 15-17us, wall 42-45us; gap = latency + drain tail.
// Fix: PRE-BIN faces per (batch, 16x16 tile).  bin_kernel (256 waves) ballots
// the 1600 bboxes vs each bin's 80x80 window, writes compacted, order-
// preserving index lists padded to x32 with an always-miss pad face.  Raster
// work unit = fixed 32-entry piece: no cull, no mask walk, uniform 16-iter
// blocks; all 32 indices loaded up front so the compiler pipelines the
// scalar record loads across iterations (addresses available early).
// Math path unchanged: bit-identical to numpy (contract off, reference op
// order, s=+-1 folds exact, cross-mult min, one IEEE divide per pixel).

#pragma clang fp contract(off)

#define H_OUT 128
#define W_OUT 128
#define NV 778
#define NF 1538
#define NB 4
#define NFP 1600                   // padded faces per batch (pads always-miss)
#define CAP 2048                   // list capacity per bin (max bin ~1100)
#define NPIECE 64                  // CAP/32
#define BG100 0x42C80000u          // 100.0f bits (uint order == float order >0)

// data record (16 floats / 64B):
// [0]s*dx12 [1]s*dy12 [2]s*dx02 [3]s*dy02 [4]s*dx01 [5]s*dy01
// [6]x0 [7]y0 [8]x1 [9]y1 [10]x2 [11]y2  [12]z0 [13]z1 [14]z2 [15]s*area
// bbox record (4 floats): xmin, xmax, ymin, ymax  (pad: inverted -> unbinned)

__global__ __launch_bounds__(256) void prep_kernel(
    const float* __restrict__ verts,   // [NB][NV][3]
    const int* __restrict__ faces,     // [NF][3]
    float* __restrict__ bbox,          // [NB*NFP][4]
    float* __restrict__ data,          // [NB*NFP][16]
    unsigned int* __restrict__ outu)   // [NB*16384]
{
    int t = blockIdx.x * 256 + threadIdx.x;   // grid 256 blocks = 65536
    outu[t] = BG100;                           // init z-buffer to 100.0f
    if (t >= NB * NFP) return;
    int b = t / NFP;
    int f = t - b * NFP;
    float* bb = bbox + (size_t)t * 4;
    float* o  = data + (size_t)t * 16;
    if (f >= NF) {                             // pad face: never binned, and
        bb[0] = 1e30f; bb[1] = -1e30f; bb[2] = 1e30f; bb[3] = -1e30f;
        o[0] = 0.0f; o[1] = 1.0f;              // e0 = -(px+1e30) < 0 -> miss
        o[2] = 0.0f; o[3] = 0.0f; o[4] = 0.0f; o[5] = 0.0f;
        o[6] = 0.0f; o[7] = 0.0f; o[8] = -1e30f; o[9] = 0.0f;
        o[10] = 0.0f; o[11] = 0.0f; o[12] = 0.0f; o[13] = 0.0f; o[14] = 0.0f;
        o[15] = 1.0f;                          // harmless area
        return;
    }
    int i0 = faces[f * 3 + 0];
    int i1 = faces[f * 3 + 1];
    int i2 = faces[f * 3 + 2];
    const float* vb = verts + (size_t)b * NV * 3;
    float x0 = vb[i0 * 3 + 0], y0 = vb[i0 * 3 + 1], z0 = vb[i0 * 3 + 2];
    float x1 = vb[i1 * 3 + 0], y1 = vb[i1 * 3 + 1], z1 = vb[i1 * 3 + 2];
    float x2 = vb[i2 * 3 + 0], y2 = vb[i2 * 3 + 1], z2 = vb[i2 * 3 + 2];

    // Reference deltas (single RN subtracts) and area (reference op order).
    float dx12 = x2 - x1, dy12 = y2 - y1;
    float dx02 = x0 - x2, dy02 = y0 - y2;
    float dx01 = x1 - x0, dy01 = y1 - y0;
    float y20 = y2 - y0, x20 = x2 - x0;
    float area = dx01 * y20 - dy01 * x20;

    float s = 0.0f;
    if (fabsf(area) > 1e-12f) s = (area > 0.0f) ? 1.0f : -1.0f;

    float xmin = fminf(fminf(x0, x1), x2), xmax = fmaxf(fmaxf(x0, x1), x2);
    float ymin = fminf(fminf(y0, y1), y2), ymax = fmaxf(fmaxf(y0, y1), y2);
    if (s == 0.0f) { xmin = 1e30f; xmax = -1e30f; }  // degenerate -> unbinned

    bb[0] = xmin; bb[1] = xmax; bb[2] = ymin; bb[3] = ymax;

    o[0] = s * dx12; o[1] = s * dy12;        // exact sign folds (s = +-1)
    o[2] = s * dx02; o[3] = s * dy02;
    o[4] = s * dx01; o[5] = s * dy01;
    o[6] = x0;  o[7] = y0;  o[8] = x1;  o[9] = y1;  o[10] = x2; o[11] = y2;
    o[12] = z0; o[13] = z1; o[14] = z2; o[15] = s * area;   // = |area| > 0
}

__global__ __launch_bounds__(64) void bin_kernel(
    const float* __restrict__ bbox,    // [NB*NFP][4]
    unsigned int* __restrict__ list,   // [256][CAP] face indices (batch-local)
    unsigned int* __restrict__ count)  // [256] padded counts (x32)
{
    int bin = blockIdx.x;              // 256 = batch(4) x tile(64)
    int b = bin >> 6, tile = bin & 63;
    int tx = tile & 7, ty = tile >> 3;
    int lane = threadIdx.x;            // one wave

    float px_lo = 80.0f * (float)tx + 2.5f, px_hi = px_lo + 75.0f;
    float py_lo = 80.0f * (float)ty + 2.5f, py_hi = py_lo + 75.0f;

    unsigned int* lp = list + (size_t)bin * CAP;
    unsigned int base = 0;
    for (int c = 0; c < NFP / 64; ++c) {
        int f = c * 64 + lane;
        float4 bb = *(const float4*)&bbox[(size_t)(b * NFP + f) * 4];
        bool ov = !(bb.x > px_hi || bb.y < px_lo ||
                    bb.z > py_hi || bb.w < py_lo);
        unsigned long long m = __ballot(ov);
        if (ov) {
            int pre = __popcll(m & ((1ull << lane) - 1ull));
            lp[base + pre] = (unsigned int)f;       // order-preserving
        }
        base += (unsigned int)__popcll(m);
    }
    // Pad to a multiple of 32 with the always-miss pad face (NFP-1).
    unsigned int padN = (32u - (base & 31u)) & 31u;
    if ((unsigned int)lane < padN) lp[base + lane] = NFP - 1;
    if (lane == 0) count[bin] = base + padN;
}

__device__ __forceinline__ void face_pair(
    const float* __restrict__ data, int gb, unsigned int fa, unsigned int fb,
    float px, float py0, float nb[4], float ab[4])
{
    int u0 = __builtin_amdgcn_readfirstlane((int)fa);
    int u1 = __builtin_amdgcn_readfirstlane((int)fb);
    const float4* p0 = (const float4*)(data + (size_t)(gb + u0) * 16);
    const float4* p1 = (const float4*)(data + (size_t)(gb + u1) * 16);
    float4 A0 = p0[0], B0 = p0[1], C0 = p0[2], D0 = p0[3];
    float4 A1 = p1[0], B1 = p1[1], C1 = p1[2], D1 = p1[3];

    #pragma unroll
    for (int k = 0; k < 4; ++k) {
        float py = py0 + 20.0f * (float)k;   // exact (multiples of 2.5)
        float nbk = nb[k], abk = ab[k];

        // face 0 (bit-exact reference op order; s folded in prep)
        float e0 = A0.x * (py - C0.y) - A0.y * (px - C0.x);
        float e1 = A0.z * (py - C0.w) - A0.w * (px - C0.z);
        float e2 = B0.x * (py - B0.w) - B0.y * (px - B0.z);
        bool in0 = (e0 >= 0.0f) & (e1 >= 0.0f) & (e2 >= 0.0f);
        float n0 = ((e0 * D0.x) + (e1 * D0.y)) + (e2 * D0.z);
        bool t0 = in0 & (n0 * abk < nbk * D0.w);  // cross-mult min (>=0)
        nbk = t0 ? n0 : nbk;  abk = t0 ? D0.w : abk;

        // face 1
        float h0 = A1.x * (py - C1.y) - A1.y * (px - C1.x);
        float h1 = A1.z * (py - C1.w) - A1.w * (px - C1.z);
        float h2 = B1.x * (py - B1.w) - B1.y * (px - B1.z);
        bool in1 = (h0 >= 0.0f) & (h1 >= 0.0f) & (h2 >= 0.0f);
        float n1 = ((h0 * D1.x) + (h1 * D1.y)) + (h2 * D1.z);
        bool t1 = in1 & (n1 * abk < nbk * D1.w);
        nbk = t1 ? n1 : nbk;  abk = t1 ? D1.w : abk;

        nb[k] = nbk; ab[k] = abk;
    }
}

__global__ __launch_bounds__(64) void raster_kernel(
    const float* __restrict__ data,    // [NB*NFP][16]
    const unsigned int* __restrict__ list,   // [256][CAP]
    const unsigned int* __restrict__ count,  // [256]
    unsigned int* __restrict__ outu)   // [NB*16384], init 100.0f bits
{
    int blk = blockIdx.x;              // 16384 = bin(256) x piece(64)
    int bin = blk >> 6, piece = blk & 63;
    unsigned int cnt = count[bin];     // wave-uniform
    if ((unsigned int)(piece * 32) >= cnt) return;   // empty piece

    int b = bin >> 6, tile = bin & 63;
    int tx = tile & 7, ty = tile >> 3;
    int lane = threadIdx.x;            // 64 threads = 1 wave
    int col = lane & 15;
    int rg  = lane >> 4;               // lane rows: rg + 4k, k=0..3
    int j = tx * 16 + col;
    int i0r = ty * 16 + rg;
    float px  = 5.0f * (float)j + 2.5f;
    float py0 = 5.0f * (float)i0r + 2.5f;
    int gb = b * NFP;

    // Load all 32 piece indices up front (uniform address) -> every face
    // record's address is known at piece start; compiler pipelines s_loads.
    const uint4* lp = (const uint4*)(list + (size_t)bin * CAP + piece * 32);
    uint4 I[8];
    #pragma unroll
    for (int q = 0; q < 8; ++q) I[q] = lp[q];

    float nb[4] = {1e10f, 1e10f, 1e10f, 1e10f};
    float ab[4] = {1.0f, 1.0f, 1.0f, 1.0f};

    #pragma unroll
    for (int q = 0; q < 8; ++q) {
        face_pair(data, gb, I[q].x, I[q].y, px, py0, nb, ab);
        face_pair(data, gb, I[q].z, I[q].w, px, py0, nb, ab);
    }

    // Epilogue: one IEEE divide + atomic per pixel (4 per lane).
    unsigned int* slot0 = &outu[(size_t)b * (H_OUT * W_OUT) + i0r * W_OUT + j];
    #pragma unroll
    for (int k = 0; k < 4; ++k) {
        float z = nb[k] / ab[k];       // winner: bit-exact reference quotient
        z += 0.0f;                     // -0.0 -> +0.0 for uint ordering
        if (z < 1e9f)                  // no-hit sentinel (1e10) -> keep bg 100
            atomicMin(slot0 + k * 4 * W_OUT, __float_as_uint(fminf(z, 100.0f)));
    }
}

extern "C" void kernel_launch(void* const* d_in, const int* in_sizes, int n_in,
                              void* d_out, int out_size, void* d_ws, size_t ws_size,
                              hipStream_t stream) {
    const float* verts = (const float*)d_in[0];   // [4][778][3] f32
    const int*   faces = (const int*)d_in[1];     // [1538][3] i32
    float* out = (float*)d_out;                   // [4][128][128] f32
    float* bbox = (float*)d_ws;                        // 102 KB
    float* data = bbox + (size_t)NB * NFP * 4;         // 410 KB
    unsigned int* list = (unsigned int*)(data + (size_t)NB * NFP * 16); // 2 MB
    unsigned int* count = list + (size_t)256 * CAP;    // 1 KB

    prep_kernel<<<256, 256, 0, stream>>>(verts, faces, bbox, data,
                                         (unsigned int*)out);
    bin_kernel<<<256, 64, 0, stream>>>(bbox, list, count);
    raster_kernel<<<256 * NPIECE, 64, 0, stream>>>(
        data, list, count, (unsigned int*)out);
}

// Round 12
// 101.921 us; speedup vs baseline: 1.4490x; 1.4490x over previous
//
#include <hip/hip_runtime.h>

// Depth rasterization, MI355X — round 12.
// R11 post-mortem: binning concept never really ran — float nb[4]/ab[4]
// passed by pointer into face_pair defeated SROA -> accumulators in SCRATCH
// (VGPR 12->76, FETCH +1MB, VALU-time 16->36us at identical face-visit
// count).  Fix the codegen, keep the binning: straight-line macros, named
// scalars only, records via wave-uniform s_load; piece-pair 128-thr blocks
// (2 waves) so 16WG/CU x 2 = 32 waves/CU; piece-major dispatch puts uniform
// active blocks first.  k-invariant hx hoist (exact value reuse).
// Math path bit-identical to numpy: contract off, reference op order,
// s=+-1 folds exact, cross-mult min, one IEEE divide per pixel.

#pragma clang fp contract(off)

#define H_OUT 128
#define W_OUT 128
#define NV 778
#define NF 1538
#define NB 4
#define NFP 1600                   // padded faces per batch (pads always-miss)
#define CAP 2048                   // list capacity per bin (max bin ~1100)
#define BG100 0x42C80000u          // 100.0f bits (uint order == float order >0)

// data record (16 floats / 64B):
// [0]s*dx12 [1]s*dy12 [2]s*dx02 [3]s*dy02 [4]s*dx01 [5]s*dy01
// [6]x0 [7]y0 [8]x1 [9]y1 [10]x2 [11]y2  [12]z0 [13]z1 [14]z2 [15]s*area
// bbox record (4 floats): xmin, xmax, ymin, ymax  (pad: inverted -> unbinned)

__global__ __launch_bounds__(256) void prep_kernel(
    const float* __restrict__ verts,   // [NB][NV][3]
    const int* __restrict__ faces,     // [NF][3]
    float* __restrict__ bbox,          // [NB*NFP][4]
    float* __restrict__ data,          // [NB*NFP][16]
    unsigned int* __restrict__ outu)   // [NB*16384]
{
    int t = blockIdx.x * 256 + threadIdx.x;   // grid 256 blocks = 65536
    outu[t] = BG100;                           // init z-buffer to 100.0f
    if (t >= NB * NFP) return;
    int b = t / NFP;
    int f = t - b * NFP;
    float* bb = bbox + (size_t)t * 4;
    float* o  = data + (size_t)t * 16;
    if (f >= NF) {                             // pad face: never binned; as a
        bb[0] = 1e30f; bb[1] = -1e30f; bb[2] = 1e30f; bb[3] = -1e30f;
        o[0] = 0.0f; o[1] = 1.0f;              // list pad: e0 = -(px+1e30) < 0
        o[2] = 0.0f; o[3] = 0.0f; o[4] = 0.0f; o[5] = 0.0f;
        o[6] = 0.0f; o[7] = 0.0f; o[8] = -1e30f; o[9] = 0.0f;
        o[10] = 0.0f; o[11] = 0.0f; o[12] = 0.0f; o[13] = 0.0f; o[14] = 0.0f;
        o[15] = 1.0f;                          // harmless area
        return;
    }
    int i0 = faces[f * 3 + 0];
    int i1 = faces[f * 3 + 1];
    int i2 = faces[f * 3 + 2];
    const float* vb = verts + (size_t)b * NV * 3;
    float x0 = vb[i0 * 3 + 0], y0 = vb[i0 * 3 + 1], z0 = vb[i0 * 3 + 2];
    float x1 = vb[i1 * 3 + 0], y1 = vb[i1 * 3 + 1], z1 = vb[i1 * 3 + 2];
    float x2 = vb[i2 * 3 + 0], y2 = vb[i2 * 3 + 1], z2 = vb[i2 * 3 + 2];

    // Reference deltas (single RN subtracts) and area (reference op order).
    float dx12 = x2 - x1, dy12 = y2 - y1;
    float dx02 = x0 - x2, dy02 = y0 - y2;
    float dx01 = x1 - x0, dy01 = y1 - y0;
    float y20 = y2 - y0, x20 = x2 - x0;
    float area = dx01 * y20 - dy01 * x20;

    float s = 0.0f;
    if (fabsf(area) > 1e-12f) s = (area > 0.0f) ? 1.0f : -1.0f;

    float xmin = fminf(fminf(x0, x1), x2), xmax = fmaxf(fmaxf(x0, x1), x2);
    float ymin = fminf(fminf(y0, y1), y2), ymax = fmaxf(fmaxf(y0, y1), y2);
    if (s == 0.0f) { xmin = 1e30f; xmax = -1e30f; }  // degenerate -> unbinned

    bb[0] = xmin; bb[1] = xmax; bb[2] = ymin; bb[3] = ymax;

    o[0] = s * dx12; o[1] = s * dy12;        // exact sign folds (s = +-1)
    o[2] = s * dx02; o[3] = s * dy02;
    o[4] = s * dx01; o[5] = s * dy01;
    o[6] = x0;  o[7] = y0;  o[8] = x1;  o[9] = y1;  o[10] = x2; o[11] = y2;
    o[12] = z0; o[13] = z1; o[14] = z2; o[15] = s * area;   // = |area| > 0
}

__global__ __launch_bounds__(64) void bin_kernel(
    const float* __restrict__ bbox,    // [NB*NFP][4]
    unsigned int* __restrict__ list,   // [256][CAP] face indices (batch-local)
    unsigned int* __restrict__ count)  // [256] padded counts (x32)
{
    int bin = blockIdx.x;              // 256 = batch(4) x tile(64)
    int b = bin >> 6, tile = bin & 63;
    int tx = tile & 7, ty = tile >> 3;
    int lane = threadIdx.x;            // one wave

    float px_lo = 80.0f * (float)tx + 2.5f, px_hi = px_lo + 75.0f;
    float py_lo = 80.0f * (float)ty + 2.5f, py_hi = py_lo + 75.0f;

    unsigned int* lp = list + (size_t)bin * CAP;
    unsigned int base = 0;
    for (int c = 0; c < NFP / 64; ++c) {
        int f = c * 64 + lane;
        float4 bb = *(const float4*)&bbox[(size_t)(b * NFP + f) * 4];
        bool ov = !(bb.x > px_hi || bb.y < px_lo ||
                    bb.z > py_hi || bb.w < py_lo);
        unsigned long long m = __ballot(ov);
        if (ov) {
            int pre = __popcll(m & ((1ull << lane) - 1ull));
            lp[base + pre] = (unsigned int)f;       // order-preserving
        }
        base += (unsigned int)__popcll(m);
    }
    // Pad to a multiple of 32 with the always-miss pad face (NFP-1).
    unsigned int padN = (32u - (base & 31u)) & 31u;
    if ((unsigned int)lane < padN) lp[base + lane] = NFP - 1;
    if (lane == 0) count[bin] = base + padN;
}

// One pixel-row update (named accumulators; exact reference op order).
#define PIX(PY, NBv, ABv)                                                   \
    {                                                                       \
        float e0 = A.x * ((PY) - C.y) - hx0;                                \
        float e1 = A.z * ((PY) - C.w) - hx1;                                \
        float e2 = B.x * ((PY) - B.w) - hx2;                                \
        bool ins = (e0 >= 0.0f) & (e1 >= 0.0f) & (e2 >= 0.0f);              \
        float n = ((e0 * D.x) + (e1 * D.y)) + (e2 * D.z);                   \
        bool tk = ins & (n * (ABv) < (NBv) * D.w);                          \
        NBv = tk ? n : (NBv);  ABv = tk ? D.w : (ABv);                      \
    }

// One face: wave-uniform index -> scalar record loads; hx* are k-invariant
// (exact VALUE reuse of A.y*(px-x1) etc., bit-identical to recomputation).
#define FACE(IDX)                                                           \
    {                                                                       \
        const float4* _p =                                                  \
            (const float4*)(data + (size_t)(gb + (int)(IDX)) * 16);         \
        float4 A = _p[0], B = _p[1], C = _p[2], D = _p[3];                  \
        float hx0 = A.y * (px - C.x);                                       \
        float hx1 = A.w * (px - C.z);                                       \
        float hx2 = B.y * (px - B.z);                                       \
        PIX(py0, nb0, ab0)                                                  \
        PIX(py1, nb1, ab1)                                                  \
        PIX(py2, nb2, ab2)                                                  \
        PIX(py3, nb3, ab3)                                                  \
    }

__global__ __launch_bounds__(128) void raster_kernel(
    const float* __restrict__ data,          // [NB*NFP][16]
    const unsigned int* __restrict__ list,   // [256][CAP]
    const unsigned int* __restrict__ count,  // [256]
    unsigned int* __restrict__ outu)         // [NB*16384], init 100.0f bits
{
    int blk = blockIdx.x;              // 8192 = piecepair(32) x bin(256)
    int bin = blk & 255;               // piece-major: active blocks first
    int pp  = blk >> 8;
    int tid = threadIdx.x;             // 128 thr = 2 waves = 2 pieces
    int w = __builtin_amdgcn_readfirstlane(tid >> 6);
    int piece = pp * 2 + w;

    unsigned int cnt = count[bin];     // wave-uniform s_load
    if ((unsigned int)(piece * 32) >= cnt) return;   // empty piece

    int b = bin >> 6, tile = bin & 63;
    int tx = tile & 7, ty = tile >> 3;
    int lane = tid & 63;
    int col = lane & 15;
    int rg  = lane >> 4;               // lane rows: rg + 4k, k = 0..3
    int j = tx * 16 + col;
    int i0r = ty * 16 + rg;
    float px  = 5.0f * (float)j + 2.5f;
    float py0 = 5.0f * (float)i0r + 2.5f;    // +20k exact (multiples of 2.5)
    float py1 = py0 + 20.0f, py2 = py0 + 40.0f, py3 = py0 + 60.0f;
    int gb = b * NFP;

    const unsigned int* lp = list + (size_t)bin * CAP + piece * 32;

    float nb0 = 1e10f, ab0 = 1.0f;     // named accumulators (registers)
    float nb1 = 1e10f, ab1 = 1.0f;
    float nb2 = 1e10f, ab2 = 1.0f;
    float nb3 = 1e10f, ab3 = 1.0f;

    // 8 groups of 4 faces; ~3KB loop body (I$-safe).  Index + record loads
    // are wave-uniform -> scalar path; TLP (up to 32 waves/CU) hides waits.
    for (int q = 0; q < 8; ++q) {
        uint4 I = *(const uint4*)(lp + q * 4);   // uniform s_load_dwordx4
        FACE(I.x)
        FACE(I.y)
        FACE(I.z)
        FACE(I.w)
    }

    // Epilogue: one IEEE divide + atomic per pixel (4 per lane).
    unsigned int* slot0 = &outu[(size_t)b * (H_OUT * W_OUT) + i0r * W_OUT + j];
    {
        float z = nb0 / ab0; z += 0.0f;
        if (z < 1e9f) atomicMin(slot0, __float_as_uint(fminf(z, 100.0f)));
    }
    {
        float z = nb1 / ab1; z += 0.0f;
        if (z < 1e9f) atomicMin(slot0 + 4 * W_OUT, __float_as_uint(fminf(z, 100.0f)));
    }
    {
        float z = nb2 / ab2; z += 0.0f;
        if (z < 1e9f) atomicMin(slot0 + 8 * W_OUT, __float_as_uint(fminf(z, 100.0f)));
    }
    {
        float z = nb3 / ab3; z += 0.0f;
        if (z < 1e9f) atomicMin(slot0 + 12 * W_OUT, __float_as_uint(fminf(z, 100.0f)));
    }
}

extern "C" void kernel_launch(void* const* d_in, const int* in_sizes, int n_in,
                              void* d_out, int out_size, void* d_ws, size_t ws_size,
                              hipStream_t stream) {
    const float* verts = (const float*)d_in[0];   // [4][778][3] f32
    const int*   faces = (const int*)d_in[1];     // [1538][3] i32
    float* out = (float*)d_out;                   // [4][128][128] f32
    float* bbox = (float*)d_ws;                        // 102 KB
    float* data = bbox + (size_t)NB * NFP * 4;         // 410 KB
    unsigned int* list = (unsigned int*)(data + (size_t)NB * NFP * 16); // 2 MB
    unsigned int* count = list + (size_t)256 * CAP;    // 1 KB

    prep_kernel<<<256, 256, 0, stream>>>(verts, faces, bbox, data,
                                         (unsigned int*)out);
    bin_kernel<<<256, 64, 0, stream>>>(bbox, list, count);
    raster_kernel<<<32 * 256, 128, 0, stream>>>(
        data, list, count, (unsigned int*)out);
}